// Round 8
// baseline (275.618 us; speedup 1.0000x reference)
//
#include <hip/hip_runtime.h>

#define B_   2
#define C_   1024
#define L_   2048
#define H_   16
#define HD_  64
#define BH_  (B_*H_)
#define N_   (B_*L_)
#define SCALE_ (1.0f/(1024.0f*2048.0f))

typedef __attribute__((ext_vector_type(8))) short short8;
typedef __attribute__((ext_vector_type(4))) short bs4;
typedef __attribute__((ext_vector_type(4))) float f32x4;

#define MFMA(a,b,c) __builtin_amdgcn_mfma_f32_16x16x32_bf16((a),(b),(c),0,0,0)

#define GLOAD16(gp, lp) \
  __builtin_amdgcn_global_load_lds( \
      (const __attribute__((address_space(1))) void*)(gp), \
      (__attribute__((address_space(3))) void*)(lp), 16, 0, 0)

__device__ __forceinline__ unsigned short f2b(float f) {
    union { float f; unsigned u; } v; v.f = f;
    unsigned r = (v.u + 0x7fffu + ((v.u >> 16) & 1u)) >> 16;
    return (unsigned short)r;
}
__device__ __forceinline__ bs4 pack4(f32x4 e) {
    union { f32x4 v; unsigned u[4]; } a; a.v = e;
    union { bs4 s; unsigned u[2]; } r;
    r.u[0] = __builtin_amdgcn_perm(a.u[1] + 0x8000u, a.u[0] + 0x8000u, 0x07060302u);
    r.u[1] = __builtin_amdgcn_perm(a.u[3] + 0x8000u, a.u[2] + 0x8000u, 0x07060302u);
    return r.s;
}
__device__ __forceinline__ float b2f(unsigned short s) {
    union { unsigned u; float f; } v; v.u = ((unsigned)s) << 16; return v.f;
}

// ---------------------------------------------------------------------------
// wprep: blocks 0..4095 convert kw/pw/c1w/c2w fp32->bf16;
//        blocks 4096..4351 transpose qw -> qwT bf16 (block 4096 also zeros X1)
// ---------------------------------------------------------------------------
struct Ptr4 { const float* p[4]; };
__global__ __launch_bounds__(256) void wprep(
    Ptr4 src, unsigned short* __restrict__ dst,
    const float* __restrict__ qw, unsigned short* __restrict__ qwT,
    float* __restrict__ X1)
{
    const int bx = blockIdx.x, t = threadIdx.x;
    if (bx < 4096) {
        const float* s = src.p[bx >> 10];
        unsigned short* d = dst + (size_t)(bx >> 10) * ((size_t)C_ * C_);
        int i = (((bx & 1023) * 256) + t) * 4;
        float4 v = *(const float4*)(s + i);
        ushort4 o;
        o.x = f2b(v.x); o.y = f2b(v.y); o.z = f2b(v.z); o.w = f2b(v.w);
        *(ushort4*)(d + i) = o;
        return;
    }
    const int tb = bx - 4096;
    if (tb == 0) {   // zero X1 (2048 floats)
        ((float4*)X1)[t] = float4{0.f, 0.f, 0.f, 0.f};
        ((float4*)X1)[256 + t] = float4{0.f, 0.f, 0.f, 0.f};
    }
    const int d0 = (tb >> 4) * 64, c0 = (tb & 15) * 64;
    __shared__ float T[64][65];
    const int tr = t >> 6, tc = t & 63;
#pragma unroll
    for (int r = 0; r < 16; ++r)
        T[r * 4 + tr][tc] = qw[(size_t)(d0 + r * 4 + tr) * C_ + c0 + tc];
    __syncthreads();
#pragma unroll
    for (int r = 0; r < 16; ++r) {
        int cc = r * 4 + tr;
        qwT[(size_t)(c0 + cc) * C_ + d0 + tc] = f2b(T[tc][cc]);
    }
}

// x f32 [b][c][l] -> xN bf16 [b][c][l], xT bf16 [b*2048+l][c], X1[b][c]=sum_l x
__global__ __launch_bounds__(256) void prep_x(
    const float* __restrict__ x, unsigned short* __restrict__ xN,
    unsigned short* __restrict__ xT, float* __restrict__ X1)
{
    int b = blockIdx.z, c0 = blockIdx.y * 64, l0 = blockIdx.x * 64;
    __shared__ float T[64][65];
    const float* xb = x + (size_t)b * C_ * L_;
    int tc = threadIdx.x >> 6;
    int tl = threadIdx.x & 63;
#pragma unroll
    for (int r = 0; r < 16; ++r) {
        int c = c0 + r * 4 + tc;
        float v = xb[(size_t)c * L_ + l0 + tl];
        T[r * 4 + tc][tl] = v;
        xN[((size_t)b * C_ + c) * L_ + l0 + tl] = f2b(v);
        float s = v;
#pragma unroll
        for (int d = 1; d < 64; d <<= 1) s += __shfl_xor(s, d);
        if (tl == 0) atomicAdd(&X1[b * C_ + c], s);
    }
    __syncthreads();
#pragma unroll
    for (int r = 0; r < 16; ++r) {
        int lr = r * 4 + tc;
        xT[((size_t)b * L_ + l0 + lr) * C_ + c0 + tl] = f2b(T[tl][lr]);
    }
}

// ---------------------------------------------------------------------------
// Gram: G[b][c1][c2] = sum_l xN[b,c1,l]*xN[b,c2,l].  64x64 tile, dbuf, 512 blk.
// ---------------------------------------------------------------------------
__global__ __launch_bounds__(256) void gram(
    const unsigned short* __restrict__ xN, unsigned short* __restrict__ G)
{
    const int t = threadIdx.x, w = t >> 6, lane = t & 63;
    const int b = blockIdx.z;
    const int c10 = blockIdx.y * 64, c20 = blockIdx.x * 64;
    const int l15 = lane & 15, q8 = (lane >> 4) * 8, q4 = (lane >> 4) * 4;
    const int wm = (w >> 1) * 32, wn = (w & 1) * 32;
    const unsigned short* xb = xN + (size_t)b * C_ * L_;

    __shared__ union {
        struct { __align__(16) unsigned short A[2][64 * 32];
                 __align__(16) unsigned short Bs[2][64 * 32]; } st;
        __align__(16) unsigned short Cs[64 * 72];
    } u;

    auto stage = [&](int buf, int k0) {
        int row = t >> 2, off = (t & 3) * 8;
        GLOAD16(&xb[(size_t)(c10 + row) * L_ + k0 + off], &u.st.A[buf][(w * 64) * 8]);
        GLOAD16(&xb[(size_t)(c20 + row) * L_ + k0 + off], &u.st.Bs[buf][(w * 64) * 8]);
    };

    f32x4 acc[2][2] = {};
    stage(0, 0);
    for (int kt = 0; kt < 64; ++kt) {
        const int cur = kt & 1;
        __syncthreads();
        if (kt < 63) stage(cur ^ 1, (kt + 1) * 32);
        short8 a[2], bf[2];
#pragma unroll
        for (int mi = 0; mi < 2; ++mi)
            a[mi] = *(const short8*)&u.st.A[cur][(wm + mi * 16 + l15) * 32 + q8];
#pragma unroll
        for (int ni = 0; ni < 2; ++ni)
            bf[ni] = *(const short8*)&u.st.Bs[cur][(wn + ni * 16 + l15) * 32 + q8];
#pragma unroll
        for (int mi = 0; mi < 2; ++mi)
#pragma unroll
            for (int ni = 0; ni < 2; ++ni)
                acc[mi][ni] = MFMA(a[mi], bf[ni], acc[mi][ni]);
    }

    __syncthreads();
#pragma unroll
    for (int mi = 0; mi < 2; ++mi)
#pragma unroll
        for (int r = 0; r < 4; ++r)
#pragma unroll
            for (int ni = 0; ni < 2; ++ni)
                u.Cs[(wm + mi * 16 + q4 + r) * 72 + wn + ni * 16 + l15] =
                    f2b(acc[mi][ni][r]);
    __syncthreads();
#pragma unroll
    for (int p = 0; p < 2; ++p) {
        int E = p * 256 + t;
        int row = E >> 3, seg = E & 7;
        short8 val = *(const short8*)&u.Cs[row * 72 + seg * 8];
        *(short8*)&G[((size_t)b * C_ + c10 + row) * C_ + c20 + seg * 8] = val;
    }
}

// ---------------------------------------------------------------------------
// mid_ab (grid 32 = bh):
//  ph1: A_h[c,d] = sum_cc G[b][h*64+c][cc]*kw[h*64+d][cc] + X1[c]*kb[d] -> LDS
//       cvec[b][h*64+c] = X1[c]/2048 + (A_h·qb)[c]*SCALE_
//  ph2: BallT[b][cc][h*64+c] = sum_d A_h[c,d]*qwT[cc][h*64+d]   (all cc)
// ---------------------------------------------------------------------------
__global__ __launch_bounds__(256) void mid_ab(
    const unsigned short* __restrict__ G, const unsigned short* __restrict__ kwb,
    const unsigned short* __restrict__ qwT,
    const float* __restrict__ X1, const float* __restrict__ kb,
    const float* __restrict__ qb,
    unsigned short* __restrict__ BallT, float* __restrict__ cvec)
{
    const int t = threadIdx.x, w = t >> 6, lane = t & 63;
    const int bh = blockIdx.x, b = bh >> 4, h = bh & 15;
    const int l15 = lane & 15, q8 = (lane >> 4) * 8, q4 = (lane >> 4) * 4;

    __shared__ union {
        struct { __align__(16) unsigned short Gs[2][64 * 32];
                 __align__(16) unsigned short Ks[2][64 * 32]; } st;
        __align__(16) unsigned short As[64 * 72];
    } u;

    const unsigned short* gb  = G   + ((size_t)b * C_ + h * 64) * C_;
    const unsigned short* kwh = kwb + (size_t)h * 64 * C_;

    auto stage = [&](int buf, int k0) {
        int row = t >> 2, off = (t & 3) * 8;
        GLOAD16(&gb[(size_t)row * C_ + k0 + off], &u.st.Gs[buf][(w * 64) * 8]);
        GLOAD16(&kwh[(size_t)row * C_ + k0 + off], &u.st.Ks[buf][(w * 64) * 8]);
    };

    f32x4 acc[4] = {};
    stage(0, 0);
    for (int kt = 0; kt < 32; ++kt) {
        const int cur = kt & 1;
        __syncthreads();
        if (kt < 31) stage(cur ^ 1, (kt + 1) * 32);
        short8 a = *(const short8*)&u.st.Gs[cur][(w * 16 + l15) * 32 + q8];
#pragma unroll
        for (int ni = 0; ni < 4; ++ni) {
            short8 bf = *(const short8*)&u.st.Ks[cur][(ni * 16 + l15) * 32 + q8];
            acc[ni] = MFMA(a, bf, acc[ni]);
        }
    }
    __syncthreads();   // staging dead; As reuse safe

    float x1r[4];
#pragma unroll
    for (int r = 0; r < 4; ++r)
        x1r[r] = X1[b * C_ + h * 64 + w * 16 + q4 + r];
    float ch[4] = {0.f, 0.f, 0.f, 0.f};
#pragma unroll
    for (int ni = 0; ni < 4; ++ni) {
        const int d = ni * 16 + l15;
        const float kbd = kb[h * 64 + d], qbd = qb[h * 64 + d];
#pragma unroll
        for (int r = 0; r < 4; ++r) {
            const int c = w * 16 + q4 + r;
            float a = acc[ni][r] + x1r[r] * kbd;
            u.As[c * 72 + d] = f2b(a);
            ch[r] += a * qbd;
        }
    }
#pragma unroll
    for (int r = 0; r < 4; ++r) {
#pragma unroll
        for (int dd = 1; dd < 16; dd <<= 1) ch[r] += __shfl_xor(ch[r], dd);
        if (l15 == 0)
            cvec[b * C_ + h * 64 + w * 16 + q4 + r] =
                x1r[r] * (1.0f / L_) + ch[r] * SCALE_;
    }
    __syncthreads();   // As complete

    // ph2: each wave handles 4 cc-tiles of 64
#pragma unroll
    for (int i = 0; i < 4; ++i) {
        const int cc0 = (i * 4 + w) * 64;
        // A frags from LDS, B frags direct from global (L2)
        f32x4 ac[4][4] = {};
#pragma unroll
        for (int ks = 0; ks < 2; ++ks) {
            short8 af[4], bf[4];
#pragma unroll
            for (int mi = 0; mi < 4; ++mi)
                af[mi] = *(const short8*)&u.As[(mi * 16 + l15) * 72 + ks * 32 + q8];
#pragma unroll
            for (int ni = 0; ni < 4; ++ni)
                bf[ni] = *(const short8*)&qwT[(size_t)(cc0 + ni * 16 + l15) * C_
                                              + h * 64 + ks * 32 + q8];
#pragma unroll
            for (int mi = 0; mi < 4; ++mi)
#pragma unroll
                for (int ni = 0; ni < 4; ++ni)
                    ac[mi][ni] = MFMA(af[mi], bf[ni], ac[mi][ni]);
        }
#pragma unroll
        for (int ni = 0; ni < 4; ++ni)
#pragma unroll
            for (int mi = 0; mi < 4; ++mi) {
                bs4 o = pack4(ac[mi][ni]);
                *(bs4*)&BallT[((size_t)b * C_ + cc0 + ni * 16 + l15) * C_
                              + h * 64 + mi * 16 + q4] = o;
            }
    }
}

// ---------------------------------------------------------------------------
// wy_gemm: Wy[b][o][cc] = SCALE_ * sum_c pw[o,c]*BallT[b][cc][c]. 64x64, dbuf.
// ---------------------------------------------------------------------------
__global__ __launch_bounds__(256) void wy_gemm(
    const unsigned short* __restrict__ pwb, const unsigned short* __restrict__ BallT,
    unsigned short* __restrict__ Wy)
{
    const int t = threadIdx.x, w = t >> 6, lane = t & 63;
    const int b = blockIdx.z;
    const int o0 = blockIdx.y * 64, cc0 = blockIdx.x * 64;
    const int l15 = lane & 15, q8 = (lane >> 4) * 8, q4 = (lane >> 4) * 4;
    const int wm = (w >> 1) * 32, wn = (w & 1) * 32;
    const unsigned short* Bb = BallT + (size_t)b * C_ * C_;

    __shared__ union {
        struct { __align__(16) unsigned short A[2][64 * 32];
                 __align__(16) unsigned short Bs[2][64 * 32]; } st;
        __align__(16) unsigned short Cs[64 * 72];
    } u;

    auto stage = [&](int buf, int k0) {
        int row = t >> 2, off = (t & 3) * 8;
        GLOAD16(&pwb[(size_t)(o0 + row) * C_ + k0 + off], &u.st.A[buf][(w * 64) * 8]);
        GLOAD16(&Bb[(size_t)(cc0 + row) * C_ + k0 + off], &u.st.Bs[buf][(w * 64) * 8]);
    };

    f32x4 acc[2][2] = {};
    stage(0, 0);
    for (int kt = 0; kt < 32; ++kt) {
        const int cur = kt & 1;
        __syncthreads();
        if (kt < 31) stage(cur ^ 1, (kt + 1) * 32);
        short8 a[2], bf[2];
#pragma unroll
        for (int mi = 0; mi < 2; ++mi)
            a[mi] = *(const short8*)&u.st.A[cur][(wm + mi * 16 + l15) * 32 + q8];
#pragma unroll
        for (int ni = 0; ni < 2; ++ni)
            bf[ni] = *(const short8*)&u.st.Bs[cur][(wn + ni * 16 + l15) * 32 + q8];
#pragma unroll
        for (int mi = 0; mi < 2; ++mi)
#pragma unroll
            for (int ni = 0; ni < 2; ++ni)
                acc[mi][ni] = MFMA(a[mi], bf[ni], acc[mi][ni]);
    }

    __syncthreads();
#pragma unroll
    for (int mi = 0; mi < 2; ++mi)
#pragma unroll
        for (int r = 0; r < 4; ++r)
#pragma unroll
            for (int ni = 0; ni < 2; ++ni)
                u.Cs[(wm + mi * 16 + q4 + r) * 72 + wn + ni * 16 + l15] =
                    f2b(acc[mi][ni][r] * SCALE_);
    __syncthreads();
#pragma unroll
    for (int p = 0; p < 2; ++p) {
        int E = p * 256 + t;
        int row = E >> 3, seg = E & 7;
        short8 val = *(const short8*)&u.Cs[row * 72 + seg * 8];
        *(short8*)&Wy[((size_t)b * C_ + o0 + row) * C_ + cc0 + seg * 8] = val;
    }
}

// dvec[b][o] = sum_c pwb[o,c]*cvec[b,c] + pb[o]
__global__ __launch_bounds__(256) void gemv_dvec(
    const unsigned short* __restrict__ pwb, const float* __restrict__ cvec,
    const float* __restrict__ pb, float* __restrict__ dvec)
{
    const int t = threadIdx.x, b = blockIdx.y;
    const int o = blockIdx.x * 128 + (t >> 1), part = t & 1;
    __shared__ float cv[1024];
#pragma unroll
    for (int i = 0; i < 4; ++i) cv[t + i * 256] = cvec[b * C_ + t + i * 256];
    __syncthreads();
    const int base = part * 512;
    float acc = 0.f;
#pragma unroll 8
    for (int j = 0; j < 64; ++j) {
        short8 w8 = *(const short8*)&pwb[(size_t)o * C_ + base + j * 8];
#pragma unroll
        for (int e = 0; e < 8; ++e)
            acc = fmaf(b2f((unsigned short)w8[e]), cv[base + j * 8 + e], acc);
    }
    acc += __shfl_xor(acc, 1);
    if (part == 0) dvec[b * C_ + o] = acc + pb[o];
}

// ---------------------------------------------------------------------------
// Generic GEMM: out[o][n] = sum_k A[o][k]*Bt[n][k] (+bias/relu/residuals)
// A batched via abstride (elements), bias via bstride. 128x64 tile, dbuf.
// ---------------------------------------------------------------------------
__global__ __launch_bounds__(256) void gemm_bf16(
    const unsigned short* __restrict__ A0, size_t abstride,
    const float* __restrict__ bias, int bstride,
    const unsigned short* __restrict__ Bt,
    const float* __restrict__ add0, const float* __restrict__ add1,
    float* __restrict__ outf, unsigned short* __restrict__ outT, int relu)
{
    const int t = threadIdx.x, w = t >> 6, lane = t & 63;
    const int o0 = blockIdx.y * 128, n0 = blockIdx.x * 64;
    const int b_ = n0 >> 11;
    const int l15 = lane & 15, q8 = (lane >> 4) * 8, q4 = (lane >> 4) * 4;
    const int wm = (w >> 1) * 64, wn = (w & 1) * 32;
    const unsigned short* A = A0 + (size_t)b_ * abstride;

    __shared__ union {
        struct { __align__(16) unsigned short A[2][128 * 32];
                 __align__(16) unsigned short B[2][64 * 32]; } st;
        __align__(16) unsigned short Cs[64 * 136];
    } u;
    __shared__ float biass[128];
    if (t < 128) biass[t] = bias[b_ * bstride + o0 + t];

    auto stage = [&](int buf, int k0) {
#pragma unroll
        for (int i = 0; i < 2; ++i) {
            int E = i * 256 + t;
            int row = E >> 2, off = (E & 3) * 8;
            GLOAD16(&A[(size_t)(o0 + row) * C_ + k0 + off],
                    &u.st.A[buf][(i * 256 + w * 64) * 8]);
        }
        {
            int row = t >> 2, off = (t & 3) * 8;
            GLOAD16(&Bt[(size_t)(n0 + row) * C_ + k0 + off],
                    &u.st.B[buf][(w * 64) * 8]);
        }
    };

    f32x4 acc[4][2] = {};
    stage(0, 0);
    for (int kt = 0; kt < 32; ++kt) {
        const int cur = kt & 1;
        __syncthreads();
        if (kt < 31) stage(cur ^ 1, (kt + 1) * 32);
        short8 a[4], b[2];
#pragma unroll
        for (int mi = 0; mi < 4; ++mi)
            a[mi] = *(const short8*)&u.st.A[cur][(wm + mi * 16 + l15) * 32 + q8];
#pragma unroll
        for (int ni = 0; ni < 2; ++ni)
            b[ni] = *(const short8*)&u.st.B[cur][(wn + ni * 16 + l15) * 32 + q8];
#pragma unroll
        for (int mi = 0; mi < 4; ++mi)
#pragma unroll
            for (int ni = 0; ni < 2; ++ni)
                acc[mi][ni] = MFMA(a[mi], b[ni], acc[mi][ni]);
    }

    __syncthreads();
    const int lbase = n0 & (L_ - 1);
#pragma unroll
    for (int mi = 0; mi < 4; ++mi)
#pragma unroll
        for (int r = 0; r < 4; ++r) {
            const int row = wm + mi * 16 + q4 + r;
            const float bv = biass[row];
#pragma unroll
            for (int ni = 0; ni < 2; ++ni) {
                const int col = wn + ni * 16 + l15;
                float v = acc[mi][ni][r] + bv;
                if (relu) v = fmaxf(v, 0.f);
                const size_t gidx = ((size_t)b_ * C_ + o0 + row) * L_ + lbase + col;
                if (add0) v += add0[gidx];
                if (add1) v += add1[gidx];
                if (outf) outf[gidx] = v;
                if (outT) u.Cs[col * 136 + row] = f2b(v);
            }
        }

    if (outT) {
        __syncthreads();
#pragma unroll
        for (int p = 0; p < 4; ++p) {
            int lr = p * 16 + (t >> 4);
            int g = t & 15;
            short8 val = *(const short8*)&u.Cs[lr * 136 + g * 8];
            *(short8*)(outT + (size_t)(n0 + lr) * C_ + o0 + g * 8) = val;
        }
    }
}

// ---------------------------------------------------------------------------
extern "C" void kernel_launch(void* const* d_in, const int* in_sizes, int n_in,
                              void* d_out, int out_size, void* d_ws, size_t ws_size,
                              hipStream_t stream) {
    const float* x   = (const float*)d_in[0];
    const float* kw  = (const float*)d_in[1];
    const float* kb  = (const float*)d_in[2];
    const float* qw  = (const float*)d_in[3];
    const float* qb  = (const float*)d_in[4];
    const float* pw  = (const float*)d_in[5];
    const float* pb  = (const float*)d_in[6];
    const float* c1w = (const float*)d_in[7];
    const float* c1b = (const float*)d_in[8];
    const float* c2w = (const float*)d_in[9];
    const float* c2b = (const float*)d_in[10];
    float* out = (float*)d_out;

    char* p = (char*)d_ws;
    auto carve = [&](size_t bytes) { char* r = p; p += (bytes + 255) & ~(size_t)255; return r; };
    const size_t WN = (size_t)C_ * C_;
    const size_t S  = (size_t)B_ * C_ * L_;
    unsigned short* wb    = (unsigned short*)carve(4 * WN * 2);  // kw,pw,c1w,c2w
    unsigned short* kwb   = wb;
    unsigned short* pwb   = wb + WN;
    unsigned short* c1wb  = wb + 2 * WN;
    unsigned short* c2wb  = wb + 3 * WN;
    unsigned short* qwT   = (unsigned short*)carve(WN * 2);
    unsigned short* xN    = (unsigned short*)carve(S * 2);
    unsigned short* xT    = (unsigned short*)carve(S * 2);
    float*          X1    = (float*)carve((size_t)B_ * C_ * 4);
    unsigned short* G     = (unsigned short*)carve((size_t)B_ * WN * 2);
    unsigned short* BallT = (unsigned short*)carve((size_t)B_ * WN * 2);
    float*          cvec  = (float*)carve((size_t)B_ * C_ * 4);
    unsigned short* Wy    = (unsigned short*)carve((size_t)B_ * WN * 2);
    float*          dvec  = (float*)carve((size_t)B_ * C_ * 4);
    unsigned short* yT    = (unsigned short*)carve(S * 2);
    unsigned short* rT    = (unsigned short*)carve(S * 2);
    float*          ybuf  = (float*)carve(S * 4);

    Ptr4 wsrc; wsrc.p[0] = kw; wsrc.p[1] = pw; wsrc.p[2] = c1w; wsrc.p[3] = c2w;
    wprep<<<4096 + 256, 256, 0, stream>>>(wsrc, wb, qw, qwT, X1);
    prep_x<<<dim3(L_ / 64, C_ / 64, B_), 256, 0, stream>>>(x, xN, xT, X1);

    gram<<<dim3(C_ / 64, C_ / 64, B_), 256, 0, stream>>>(xN, G);
    mid_ab<<<BH_, 256, 0, stream>>>(G, kwb, qwT, X1, kb, qb, BallT, cvec);
    wy_gemm<<<dim3(C_ / 64, C_ / 64, B_), 256, 0, stream>>>(pwb, BallT, Wy);
    gemv_dvec<<<dim3(8, B_), 256, 0, stream>>>(pwb, cvec, pb, dvec);

    dim3 gG(N_ / 64, C_ / 128);      // 64 x 8 = 512 blocks
    // y = SCALE*(pw·Ball)·x + (pw·cvec+pb) + x
    gemm_bf16<<<gG, 256, 0, stream>>>(Wy, WN, dvec, C_, xT, x, nullptr, ybuf, yT, 0);
    // r = relu(c1·y + c1b)
    gemm_bf16<<<gG, 256, 0, stream>>>(c1wb, 0, c1b, 0, yT, nullptr, nullptr, nullptr, rT, 1);
    // out = c2·r + c2b + y + x
    gemm_bf16<<<gG, 256, 0, stream>>>(c2wb, 0, c2b, 0, rT, ybuf, x, out, nullptr, 0);
}

// Round 9
// 244.708 us; speedup vs baseline: 1.1263x; 1.1263x over previous
//
#include <hip/hip_runtime.h>

#define B_   2
#define C_   1024
#define L_   2048
#define H_   16
#define HD_  64
#define BH_  (B_*H_)
#define N_   (B_*L_)
#define SCALE_ (1.0f/(1024.0f*2048.0f))

typedef __attribute__((ext_vector_type(8))) short short8;
typedef __attribute__((ext_vector_type(4))) short bs4;
typedef __attribute__((ext_vector_type(4))) float f32x4;

#define MFMA(a,b,c) __builtin_amdgcn_mfma_f32_16x16x32_bf16((a),(b),(c),0,0,0)

#define GLOAD16(gp, lp) \
  __builtin_amdgcn_global_load_lds( \
      (const __attribute__((address_space(1))) void*)(gp), \
      (__attribute__((address_space(3))) void*)(lp), 16, 0, 0)

__device__ __forceinline__ unsigned short f2b(float f) {
    union { float f; unsigned u; } v; v.f = f;
    unsigned r = (v.u + 0x7fffu + ((v.u >> 16) & 1u)) >> 16;
    return (unsigned short)r;
}
__device__ __forceinline__ bs4 pack4(f32x4 e) {
    union { f32x4 v; unsigned u[4]; } a; a.v = e;
    union { bs4 s; unsigned u[2]; } r;
    r.u[0] = __builtin_amdgcn_perm(a.u[1] + 0x8000u, a.u[0] + 0x8000u, 0x07060302u);
    r.u[1] = __builtin_amdgcn_perm(a.u[3] + 0x8000u, a.u[2] + 0x8000u, 0x07060302u);
    return r.s;
}
__device__ __forceinline__ float b2f(unsigned short s) {
    union { unsigned u; float f; } v; v.u = ((unsigned)s) << 16; return v.f;
}

// ---------------------------------------------------------------------------
// wprep: blocks 0..4095 convert kw/pw/c1w/c2w fp32->bf16;
//        blocks 4096..4351 transpose qw -> qwT bf16 (block 4096 also zeros X1)
// ---------------------------------------------------------------------------
struct Ptr4 { const float* p[4]; };
__global__ __launch_bounds__(256) void wprep(
    Ptr4 src, unsigned short* __restrict__ dst,
    const float* __restrict__ qw, unsigned short* __restrict__ qwT,
    float* __restrict__ X1)
{
    const int bx = blockIdx.x, t = threadIdx.x;
    if (bx < 4096) {
        const float* s = src.p[bx >> 10];
        unsigned short* d = dst + (size_t)(bx >> 10) * ((size_t)C_ * C_);
        int i = (((bx & 1023) * 256) + t) * 4;
        float4 v = *(const float4*)(s + i);
        ushort4 o;
        o.x = f2b(v.x); o.y = f2b(v.y); o.z = f2b(v.z); o.w = f2b(v.w);
        *(ushort4*)(d + i) = o;
        return;
    }
    const int tb = bx - 4096;
    if (tb == 0) {
        ((float4*)X1)[t] = float4{0.f, 0.f, 0.f, 0.f};
        ((float4*)X1)[256 + t] = float4{0.f, 0.f, 0.f, 0.f};
    }
    const int d0 = (tb >> 4) * 64, c0 = (tb & 15) * 64;
    __shared__ float T[64][65];
    const int tr = t >> 6, tc = t & 63;
#pragma unroll
    for (int r = 0; r < 16; ++r)
        T[r * 4 + tr][tc] = qw[(size_t)(d0 + r * 4 + tr) * C_ + c0 + tc];
    __syncthreads();
#pragma unroll
    for (int r = 0; r < 16; ++r) {
        int cc = r * 4 + tr;
        qwT[(size_t)(c0 + cc) * C_ + d0 + tc] = f2b(T[tc][cc]);
    }
}

// x f32 [b][c][l] -> xN bf16 [b][c][l], xT bf16 [b*2048+l][c], X1[b][c]=sum_l x
__global__ __launch_bounds__(256) void prep_x(
    const float* __restrict__ x, unsigned short* __restrict__ xN,
    unsigned short* __restrict__ xT, float* __restrict__ X1)
{
    int b = blockIdx.z, c0 = blockIdx.y * 64, l0 = blockIdx.x * 64;
    __shared__ float T[64][65];
    const float* xb = x + (size_t)b * C_ * L_;
    int tc = threadIdx.x >> 6;
    int tl = threadIdx.x & 63;
#pragma unroll
    for (int r = 0; r < 16; ++r) {
        int c = c0 + r * 4 + tc;
        float v = xb[(size_t)c * L_ + l0 + tl];
        T[r * 4 + tc][tl] = v;
        xN[((size_t)b * C_ + c) * L_ + l0 + tl] = f2b(v);
        float s = v;
#pragma unroll
        for (int d = 1; d < 64; d <<= 1) s += __shfl_xor(s, d);
        if (tl == 0) atomicAdd(&X1[b * C_ + c], s);
    }
    __syncthreads();
#pragma unroll
    for (int r = 0; r < 16; ++r) {
        int lr = r * 4 + tc;
        xT[((size_t)b * L_ + l0 + lr) * C_ + c0 + tl] = f2b(T[tl][lr]);
    }
}

// ---------------------------------------------------------------------------
// gram64: G[b][c1][c2] = sum_l xN[b,c1,l]*xN[b,c2,l]. 64x64, BK=64, dbuf.
// grid (16,16,B) = 512 blocks.
// ---------------------------------------------------------------------------
__global__ __launch_bounds__(256) void gram64(
    const unsigned short* __restrict__ xN, unsigned short* __restrict__ G)
{
    const int t = threadIdx.x, w = t >> 6, lane = t & 63;
    const int b = blockIdx.z;
    const int c10 = blockIdx.y * 64, c20 = blockIdx.x * 64;
    const int l15 = lane & 15, q8 = (lane >> 4) * 8, q4 = (lane >> 4) * 4;
    const int wm = (w >> 1) * 32, wn = (w & 1) * 32;
    const unsigned short* xb = xN + (size_t)b * C_ * L_;

    __shared__ union {
        __align__(16) unsigned short st[2][2][2][64 * 32]; // [buf][A/B][ks]
        __align__(16) unsigned short Cs[64 * 72];
    } u;

    auto stage = [&](int buf, int k0) {
        int row = t >> 2, off = (t & 3) * 8;
        GLOAD16(&xb[(size_t)(c10 + row) * L_ + k0 + off],      &u.st[buf][0][0][(w * 64) * 8]);
        GLOAD16(&xb[(size_t)(c10 + row) * L_ + k0 + 32 + off], &u.st[buf][0][1][(w * 64) * 8]);
        GLOAD16(&xb[(size_t)(c20 + row) * L_ + k0 + off],      &u.st[buf][1][0][(w * 64) * 8]);
        GLOAD16(&xb[(size_t)(c20 + row) * L_ + k0 + 32 + off], &u.st[buf][1][1][(w * 64) * 8]);
    };

    f32x4 acc[2][2] = {};
    stage(0, 0);
    for (int kt = 0; kt < 32; ++kt) {
        const int cur = kt & 1;
        __syncthreads();
        if (kt < 31) stage(cur ^ 1, (kt + 1) * 64);
#pragma unroll
        for (int ks = 0; ks < 2; ++ks) {
            short8 a[2], bf[2];
#pragma unroll
            for (int mi = 0; mi < 2; ++mi)
                a[mi] = *(const short8*)&u.st[cur][0][ks][(wm + mi * 16 + l15) * 32 + q8];
#pragma unroll
            for (int ni = 0; ni < 2; ++ni)
                bf[ni] = *(const short8*)&u.st[cur][1][ks][(wn + ni * 16 + l15) * 32 + q8];
#pragma unroll
            for (int mi = 0; mi < 2; ++mi)
#pragma unroll
                for (int ni = 0; ni < 2; ++ni)
                    acc[mi][ni] = MFMA(a[mi], bf[ni], acc[mi][ni]);
        }
    }

    __syncthreads();
#pragma unroll
    for (int mi = 0; mi < 2; ++mi)
#pragma unroll
        for (int r = 0; r < 4; ++r)
#pragma unroll
            for (int ni = 0; ni < 2; ++ni)
                u.Cs[(wm + mi * 16 + q4 + r) * 72 + wn + ni * 16 + l15] =
                    f2b(acc[mi][ni][r]);
    __syncthreads();
#pragma unroll
    for (int p = 0; p < 2; ++p) {
        int E = p * 256 + t;
        int row = E >> 3, seg = E & 7;
        short8 val = *(const short8*)&u.Cs[row * 72 + seg * 8];
        *(short8*)&G[((size_t)b * C_ + c10 + row) * C_ + c20 + seg * 8] = val;
    }
}

// ---------------------------------------------------------------------------
// mid_ab (grid 32 = bh):
//  ph1: A_h[c,d] = sum_cc G[b][h*64+c][cc]*kw[h*64+d][cc] + X1[c]*kb[d] -> LDS
//       cvec[b][h*64+c] = X1[c]/2048 + (A_h·qb)[c]*SCALE_
//  ph2: BallT[b][cc][h*64+c] = sum_d A_h[c,d]*qwT[cc][h*64+d]
// ---------------------------------------------------------------------------
__global__ __launch_bounds__(256) void mid_ab(
    const unsigned short* __restrict__ G, const unsigned short* __restrict__ kwb,
    const unsigned short* __restrict__ qwT,
    const float* __restrict__ X1, const float* __restrict__ kb,
    const float* __restrict__ qb,
    unsigned short* __restrict__ BallT, float* __restrict__ cvec)
{
    const int t = threadIdx.x, w = t >> 6, lane = t & 63;
    const int bh = blockIdx.x, b = bh >> 4, h = bh & 15;
    const int l15 = lane & 15, q8 = (lane >> 4) * 8, q4 = (lane >> 4) * 4;

    __shared__ union {
        struct { __align__(16) unsigned short Gs[2][64 * 32];
                 __align__(16) unsigned short Ks[2][64 * 32]; } st;
        __align__(16) unsigned short As[64 * 72];
    } u;

    const unsigned short* gb  = G   + ((size_t)b * C_ + h * 64) * C_;
    const unsigned short* kwh = kwb + (size_t)h * 64 * C_;

    auto stage = [&](int buf, int k0) {
        int row = t >> 2, off = (t & 3) * 8;
        GLOAD16(&gb[(size_t)row * C_ + k0 + off], &u.st.Gs[buf][(w * 64) * 8]);
        GLOAD16(&kwh[(size_t)row * C_ + k0 + off], &u.st.Ks[buf][(w * 64) * 8]);
    };

    f32x4 acc[4] = {};
    stage(0, 0);
    for (int kt = 0; kt < 32; ++kt) {
        const int cur = kt & 1;
        __syncthreads();
        if (kt < 31) stage(cur ^ 1, (kt + 1) * 32);
        short8 a = *(const short8*)&u.st.Gs[cur][(w * 16 + l15) * 32 + q8];
#pragma unroll
        for (int ni = 0; ni < 4; ++ni) {
            short8 bf = *(const short8*)&u.st.Ks[cur][(ni * 16 + l15) * 32 + q8];
            acc[ni] = MFMA(a, bf, acc[ni]);
        }
    }
    __syncthreads();

    float x1r[4];
#pragma unroll
    for (int r = 0; r < 4; ++r)
        x1r[r] = X1[b * C_ + h * 64 + w * 16 + q4 + r];
    float ch[4] = {0.f, 0.f, 0.f, 0.f};
#pragma unroll
    for (int ni = 0; ni < 4; ++ni) {
        const int d = ni * 16 + l15;
        const float kbd = kb[h * 64 + d], qbd = qb[h * 64 + d];
#pragma unroll
        for (int r = 0; r < 4; ++r) {
            const int c = w * 16 + q4 + r;
            float a = acc[ni][r] + x1r[r] * kbd;
            u.As[c * 72 + d] = f2b(a);
            ch[r] += a * qbd;
        }
    }
#pragma unroll
    for (int r = 0; r < 4; ++r) {
#pragma unroll
        for (int dd = 1; dd < 16; dd <<= 1) ch[r] += __shfl_xor(ch[r], dd);
        if (l15 == 0)
            cvec[b * C_ + h * 64 + w * 16 + q4 + r] =
                x1r[r] * (1.0f / L_) + ch[r] * SCALE_;
    }
    __syncthreads();

#pragma unroll
    for (int i = 0; i < 4; ++i) {
        const int cc0 = (i * 4 + w) * 64;
        f32x4 ac[4][4] = {};
#pragma unroll
        for (int ks = 0; ks < 2; ++ks) {
            short8 af[4], bf[4];
#pragma unroll
            for (int mi = 0; mi < 4; ++mi)
                af[mi] = *(const short8*)&u.As[(mi * 16 + l15) * 72 + ks * 32 + q8];
#pragma unroll
            for (int ni = 0; ni < 4; ++ni)
                bf[ni] = *(const short8*)&qwT[(size_t)(cc0 + ni * 16 + l15) * C_
                                              + h * 64 + ks * 32 + q8];
#pragma unroll
            for (int mi = 0; mi < 4; ++mi)
#pragma unroll
                for (int ni = 0; ni < 4; ++ni)
                    ac[mi][ni] = MFMA(af[mi], bf[ni], ac[mi][ni]);
        }
#pragma unroll
        for (int ni = 0; ni < 4; ++ni)
#pragma unroll
            for (int mi = 0; mi < 4; ++mi) {
                bs4 o = pack4(ac[mi][ni]);
                *(bs4*)&BallT[((size_t)b * C_ + cc0 + ni * 16 + l15) * C_
                              + h * 64 + mi * 16 + q4] = o;
            }
    }
}

// ---------------------------------------------------------------------------
// wy64: Wy[b][o][cc] = SCALE_ * sum_c pw[o,c]*BallT[b][cc][c]. 64x64 BK=64 dbuf.
// ---------------------------------------------------------------------------
__global__ __launch_bounds__(256) void wy64(
    const unsigned short* __restrict__ pwb, const unsigned short* __restrict__ BallT,
    unsigned short* __restrict__ Wy)
{
    const int t = threadIdx.x, w = t >> 6, lane = t & 63;
    const int b = blockIdx.z;
    const int o0 = blockIdx.y * 64, cc0 = blockIdx.x * 64;
    const int l15 = lane & 15, q8 = (lane >> 4) * 8, q4 = (lane >> 4) * 4;
    const int wm = (w >> 1) * 32, wn = (w & 1) * 32;
    const unsigned short* Bb = BallT + (size_t)b * C_ * C_;

    __shared__ union {
        __align__(16) unsigned short st[2][2][2][64 * 32];
        __align__(16) unsigned short Cs[64 * 72];
    } u;

    auto stage = [&](int buf, int k0) {
        int row = t >> 2, off = (t & 3) * 8;
        GLOAD16(&pwb[(size_t)(o0 + row) * C_ + k0 + off],      &u.st[buf][0][0][(w * 64) * 8]);
        GLOAD16(&pwb[(size_t)(o0 + row) * C_ + k0 + 32 + off], &u.st[buf][0][1][(w * 64) * 8]);
        GLOAD16(&Bb[(size_t)(cc0 + row) * C_ + k0 + off],      &u.st[buf][1][0][(w * 64) * 8]);
        GLOAD16(&Bb[(size_t)(cc0 + row) * C_ + k0 + 32 + off], &u.st[buf][1][1][(w * 64) * 8]);
    };

    f32x4 acc[2][2] = {};
    stage(0, 0);
    for (int kt = 0; kt < 16; ++kt) {
        const int cur = kt & 1;
        __syncthreads();
        if (kt < 15) stage(cur ^ 1, (kt + 1) * 64);
#pragma unroll
        for (int ks = 0; ks < 2; ++ks) {
            short8 a[2], bf[2];
#pragma unroll
            for (int mi = 0; mi < 2; ++mi)
                a[mi] = *(const short8*)&u.st[cur][0][ks][(wm + mi * 16 + l15) * 32 + q8];
#pragma unroll
            for (int ni = 0; ni < 2; ++ni)
                bf[ni] = *(const short8*)&u.st[cur][1][ks][(wn + ni * 16 + l15) * 32 + q8];
#pragma unroll
            for (int mi = 0; mi < 2; ++mi)
#pragma unroll
                for (int ni = 0; ni < 2; ++ni)
                    acc[mi][ni] = MFMA(a[mi], bf[ni], acc[mi][ni]);
        }
    }

    __syncthreads();
#pragma unroll
    for (int mi = 0; mi < 2; ++mi)
#pragma unroll
        for (int r = 0; r < 4; ++r)
#pragma unroll
            for (int ni = 0; ni < 2; ++ni)
                u.Cs[(wm + mi * 16 + q4 + r) * 72 + wn + ni * 16 + l15] =
                    f2b(acc[mi][ni][r] * SCALE_);
    __syncthreads();
#pragma unroll
    for (int p = 0; p < 2; ++p) {
        int E = p * 256 + t;
        int row = E >> 3, seg = E & 7;
        short8 val = *(const short8*)&u.Cs[row * 72 + seg * 8];
        *(short8*)&Wy[((size_t)b * C_ + o0 + row) * C_ + cc0 + seg * 8] = val;
    }
}

// dvec[b][o] = sum_c pwb[o,c]*cvec[b,c] + pb[o]
__global__ __launch_bounds__(256) void gemv_dvec(
    const unsigned short* __restrict__ pwb, const float* __restrict__ cvec,
    const float* __restrict__ pb, float* __restrict__ dvec)
{
    const int t = threadIdx.x, b = blockIdx.y;
    const int o = blockIdx.x * 128 + (t >> 1), part = t & 1;
    __shared__ float cv[1024];
#pragma unroll
    for (int i = 0; i < 4; ++i) cv[t + i * 256] = cvec[b * C_ + t + i * 256];
    __syncthreads();
    const int base = part * 512;
    float acc = 0.f;
#pragma unroll 8
    for (int j = 0; j < 64; ++j) {
        short8 w8 = *(const short8*)&pwb[(size_t)o * C_ + base + j * 8];
#pragma unroll
        for (int e = 0; e < 8; ++e)
            acc = fmaf(b2f((unsigned short)w8[e]), cv[base + j * 8 + e], acc);
    }
    acc += __shfl_xor(acc, 1);
    if (part == 0) dvec[b * C_ + o] = acc + pb[o];
}

// ---------------------------------------------------------------------------
// gemm64: out[o][n] = sum_k A[o][k]*Bt[n][k] (+bias/relu/residuals)
// 64x64 tile, BK=64, dbuf. Grid (N/64, 16) = 1024 blocks = 4/CU.
// Epilogue order: v=acc+bias; relu; v+=add0; outT=f2b(v); v+=add1; outf=v.
// ---------------------------------------------------------------------------
__global__ __launch_bounds__(256) void gemm64(
    const unsigned short* __restrict__ A0, size_t abstride,
    const float* __restrict__ bias, int bstride,
    const unsigned short* __restrict__ Bt,
    const float* __restrict__ add0, const float* __restrict__ add1,
    float* __restrict__ outf, unsigned short* __restrict__ outT, int relu)
{
    const int t = threadIdx.x, w = t >> 6, lane = t & 63;
    const int o0 = blockIdx.y * 64, n0 = blockIdx.x * 64;
    const int b_ = n0 >> 11;
    const int l15 = lane & 15, q8 = (lane >> 4) * 8, q4 = (lane >> 4) * 4;
    const int wm = (w >> 1) * 32, wn = (w & 1) * 32;
    const unsigned short* A = A0 + (size_t)b_ * abstride;

    __shared__ union {
        __align__(16) unsigned short st[2][2][2][64 * 32];
        __align__(16) unsigned short Cs[64 * 72];
    } u;
    __shared__ float biass[64];
    if (t < 64) biass[t] = bias[b_ * bstride + o0 + t];

    auto stage = [&](int buf, int k0) {
        int row = t >> 2, off = (t & 3) * 8;
        GLOAD16(&A[(size_t)(o0 + row) * C_ + k0 + off],       &u.st[buf][0][0][(w * 64) * 8]);
        GLOAD16(&A[(size_t)(o0 + row) * C_ + k0 + 32 + off],  &u.st[buf][0][1][(w * 64) * 8]);
        GLOAD16(&Bt[(size_t)(n0 + row) * C_ + k0 + off],      &u.st[buf][1][0][(w * 64) * 8]);
        GLOAD16(&Bt[(size_t)(n0 + row) * C_ + k0 + 32 + off], &u.st[buf][1][1][(w * 64) * 8]);
    };

    f32x4 acc[2][2] = {};
    stage(0, 0);
    for (int kt = 0; kt < 16; ++kt) {
        const int cur = kt & 1;
        __syncthreads();
        if (kt < 15) stage(cur ^ 1, (kt + 1) * 64);
#pragma unroll
        for (int ks = 0; ks < 2; ++ks) {
            short8 a[2], b[2];
#pragma unroll
            for (int mi = 0; mi < 2; ++mi)
                a[mi] = *(const short8*)&u.st[cur][0][ks][(wm + mi * 16 + l15) * 32 + q8];
#pragma unroll
            for (int ni = 0; ni < 2; ++ni)
                b[ni] = *(const short8*)&u.st[cur][1][ks][(wn + ni * 16 + l15) * 32 + q8];
#pragma unroll
            for (int mi = 0; mi < 2; ++mi)
#pragma unroll
                for (int ni = 0; ni < 2; ++ni)
                    acc[mi][ni] = MFMA(a[mi], b[ni], acc[mi][ni]);
        }
    }

    __syncthreads();
    const int lbase = n0 & (L_ - 1);
#pragma unroll
    for (int mi = 0; mi < 2; ++mi)
#pragma unroll
        for (int r = 0; r < 4; ++r) {
            const int row = wm + mi * 16 + q4 + r;
            const float bv = biass[row];
#pragma unroll
            for (int ni = 0; ni < 2; ++ni) {
                const int col = wn + ni * 16 + l15;
                float v = acc[mi][ni][r] + bv;
                if (relu) v = fmaxf(v, 0.f);
                const size_t gidx = ((size_t)b_ * C_ + o0 + row) * L_ + lbase + col;
                if (add0) v += add0[gidx];
                if (outT) u.Cs[col * 72 + row] = f2b(v);
                if (add1) v += add1[gidx];
                if (outf) outf[gidx] = v;
            }
        }

    if (outT) {
        __syncthreads();
#pragma unroll
        for (int p = 0; p < 2; ++p) {
            int E = p * 256 + t;
            int lr = E >> 3, g = E & 7;
            short8 val = *(const short8*)&u.Cs[lr * 72 + g * 8];
            *(short8*)(outT + (size_t)(n0 + lr) * C_ + o0 + g * 8) = val;
        }
    }
}

// ---------------------------------------------------------------------------
extern "C" void kernel_launch(void* const* d_in, const int* in_sizes, int n_in,
                              void* d_out, int out_size, void* d_ws, size_t ws_size,
                              hipStream_t stream) {
    const float* x   = (const float*)d_in[0];
    const float* kw  = (const float*)d_in[1];
    const float* kb  = (const float*)d_in[2];
    const float* qw  = (const float*)d_in[3];
    const float* qb  = (const float*)d_in[4];
    const float* pw  = (const float*)d_in[5];
    const float* pb  = (const float*)d_in[6];
    const float* c1w = (const float*)d_in[7];
    const float* c1b = (const float*)d_in[8];
    const float* c2w = (const float*)d_in[9];
    const float* c2b = (const float*)d_in[10];
    float* out = (float*)d_out;

    char* p = (char*)d_ws;
    auto carve = [&](size_t bytes) { char* r = p; p += (bytes + 255) & ~(size_t)255; return r; };
    const size_t WN = (size_t)C_ * C_;
    const size_t S  = (size_t)B_ * C_ * L_;
    unsigned short* wb    = (unsigned short*)carve(4 * WN * 2);  // kw,pw,c1w,c2w
    unsigned short* kwb   = wb;
    unsigned short* pwb   = wb + WN;
    unsigned short* c1wb  = wb + 2 * WN;
    unsigned short* c2wb  = wb + 3 * WN;
    unsigned short* qwT   = (unsigned short*)carve(WN * 2);
    unsigned short* xN    = (unsigned short*)carve(S * 2);
    unsigned short* xT    = (unsigned short*)carve(S * 2);
    float*          X1    = (float*)carve((size_t)B_ * C_ * 4);
    unsigned short* G     = (unsigned short*)carve((size_t)B_ * WN * 2);
    unsigned short* BallT = (unsigned short*)carve((size_t)B_ * WN * 2);
    float*          cvec  = (float*)carve((size_t)B_ * C_ * 4);
    unsigned short* Wy    = (unsigned short*)carve((size_t)B_ * WN * 2);
    float*          dvec  = (float*)carve((size_t)B_ * C_ * 4);
    unsigned short* yT    = (unsigned short*)carve(S * 2);
    unsigned short* rT    = (unsigned short*)carve(S * 2);
    float*          ybuf2 = (float*)carve(S * 4);   // holds y + x

    Ptr4 wsrc; wsrc.p[0] = kw; wsrc.p[1] = pw; wsrc.p[2] = c1w; wsrc.p[3] = c2w;
    wprep<<<4096 + 256, 256, 0, stream>>>(wsrc, wb, qw, qwT, X1);
    prep_x<<<dim3(L_ / 64, C_ / 64, B_), 256, 0, stream>>>(x, xN, xT, X1);

    gram64<<<dim3(C_ / 64, C_ / 64, B_), 256, 0, stream>>>(xN, G);
    mid_ab<<<BH_, 256, 0, stream>>>(G, kwb, qwT, X1, kb, qb, BallT, cvec);
    wy64<<<dim3(C_ / 64, C_ / 64, B_), 256, 0, stream>>>(pwb, BallT, Wy);
    gemv_dvec<<<dim3(8, B_), 256, 0, stream>>>(pwb, cvec, pb, dvec);

    dim3 gG(N_ / 64, C_ / 64);       // 64 x 16 = 1024 blocks = 4/CU
    // y = Wy·x + dvec + x ; yT = bf16(y) ; ybuf2 = y + x (second x via add1)
    gemm64<<<gG, 256, 0, stream>>>(Wy, WN, dvec, C_, xT, x, x, ybuf2, yT, 0);
    // r = relu(c1·y + c1b)
    gemm64<<<gG, 256, 0, stream>>>(c1wb, 0, c1b, 0, yT, nullptr, nullptr, nullptr, rT, 1);
    // out = c2·r + c2b + (y + x)
    gemm64<<<gG, 256, 0, stream>>>(c2wb, 0, c2b, 0, rT, ybuf2, nullptr, out, nullptr, 0);
}